// Round 2
// 482.613 us; speedup vs baseline: 1.0155x; 1.0155x over previous
//
#include <hip/hip_runtime.h>
#include <math.h>

// DirectBEVProjector: polar warp + bilinear sample.
// feat [B=4, C=256, IH=128, IW=512] f32 -> out [B, C, 128, 512] f32.
// R1: channel-split 8x (CPT=32) for TLP.
// R2: merge horizontal corner pairs (nw+ne, sw+se) into single 8B packed
//     loads -> halves gather instructions (128->64/thread) and halves
//     unique-cacheline traversals in the TA (was the bottleneck: ~20 cyc per
//     gather instr at 30% HBM BW, 20% VALU). Column clamp at ix=511 folded
//     into hoisted per-window weights so the inner loop is 2 loads + 4 FMA.
// R3: identical resubmit — R2 bench died to container-acquisition infra
//     failure (no pytest/profile ran). Kernel audited: no OOB (windows
//     within [0,511]x[0,127]), align-4 packed loads are legal on gfx950.

#define BEV_H 128
#define BEV_W 512
#define IH 128
#define IW 512
#define C_CH 256
#define B_N 4
#define CPT 32                       // channels per thread
#define GROUPS (C_CH / CPT)          // 8 channel groups

// 8-byte pair with 4-byte alignment: lets hipcc emit global_load_dwordx2 on
// an odd-column address (gfx950 supports unaligned global); worst case it
// legally splits into 2 dword loads (== old behavior).
struct __attribute__((packed, aligned(4))) f2p { float x, y; };

__global__ __launch_bounds__(256) void bev_project_kernel(
    const float* __restrict__ feat,
    const float* __restrict__ rot,
    const float* __restrict__ shift_u,
    const float* __restrict__ shift_v,
    const float* __restrict__ mpp,
    float* __restrict__ out)
{
    const float PI_F     = 3.14159265358979323846f;
    const float TWO_PI_F = 6.28318530717958647692f;

    int idx = blockIdx.x * blockDim.x + threadIdx.x;  // 0 .. 2M-1
    int j  = idx & (BEV_W - 1);         // lanes consecutive in j -> coalesced store
    int i  = (idx >> 9) & (BEV_H - 1);
    int b  = (idx >> 16) & (B_N - 1);
    int cg = idx >> 18;                 // channel group, slowest

    // ---- coordinate math (mirrors reference exactly, fp32) ----
    float cv = (float)(BEV_H / 2) - 0.5f + shift_v[b];
    float cu = (float)(BEV_W / 2) - 0.5f + shift_u[b];
    float dy = (float)i - cv;
    float dx = (float)j - cu;
    float radius = sqrtf(dy * dy + dx * dx);
    float theta = atan2f(dy, dx);

    float t = fmodf(theta, TWO_PI_F); if (t < 0.0f) t += TWO_PI_F;
    t = -PI_F * 0.5f + t;
    t = fmodf(t, TWO_PI_F); if (t < 0.0f) t += TWO_PI_F;
    t = t + rot[b] * 360.0f / 180.0f * PI_F;          // rot * 2*pi, ref op order
    t = fmodf(t, TWO_PI_F); if (t < 0.0f) t += TWO_PI_F;

    float u = t * (1.0f / TWO_PI_F) * (float)IW;
    float dist = radius * mpp[0];
    float phi = atan2f(dist, -2.0f);                  // GRD_HEIGHT = -2.0
    float v = phi * (1.0f / PI_F) * (float)IH;

    // ---- bilinear corners & weights (clamp-before-weights, faithful) ----
    float ix = u, iy = v;
    float nwx = floorf(ix), nwy = floorf(iy);

    auto cx = [](float x) { return fminf(fmaxf(x, 0.0f), (float)(IW - 1)); };
    auto cy = [](float y) { return fminf(fmaxf(y, 0.0f), (float)(IH - 1)); };

    float ix_ne = cx(nwx + 1.0f), iy_ne = cy(nwy);
    float ix_sw = cx(nwx),        iy_sw = cy(nwy + 1.0f);
    float ix_se = cx(nwx + 1.0f), iy_se = cy(nwy + 1.0f);
    float ix_nw = cx(nwx),        iy_nw = cy(nwy);

    float w_nw = (ix_se - ix) * (iy_se - iy);
    float w_ne = (ix - ix_sw) * (iy_sw - iy);
    float w_sw = (ix_ne - ix) * (iy - iy_ne);
    float w_se = (ix - ix_nw) * (iy - iy_nw);

    // ---- 2-wide window per row: fold the column clamp into weights ----
    int c0i = (int)ix_nw;            // clamped left column
    int c1i = (int)ix_ne;            // clamped right column
    int r0i = (int)iy_nw;            // top row (== iy_ne row)
    int r1i = (int)iy_sw;            // bottom row (== iy_se row)
    int s   = (c1i == c0i) ? 1 : 0;  // right edge: both corners clamp to 511
    int cb  = c0i - s; if (cb < 0) cb = 0;   // window base column

    // element weights for the 2-wide window {cb, cb+1} on each row
    float wa_x = s ? 0.0f          : w_nw;   // top row
    float wa_y = s ? (w_nw + w_ne) : w_ne;
    float wb_x = s ? 0.0f          : w_sw;   // bottom row
    float wb_y = s ? (w_sw + w_se) : w_se;

    const int cbase = cg * CPT;
    const float* fb = feat + ((size_t)b * C_CH + cbase) * (IH * IW);
    const float* p0 = fb + (size_t)r0i * IW + cb;
    const float* p1 = fb + (size_t)r1i * IW + cb;
    float* ob = out + ((size_t)b * C_CH + cbase) * (BEV_H * BEV_W)
                    + (size_t)i * BEV_W + (size_t)j;

    // ---- channel loop: 2 pair-gathers + 4 FMA, coalesced nontemporal store ----
    #pragma unroll 8
    for (int c = 0; c < CPT; ++c) {
        f2p a = *(const f2p*)p0;     // {nw, ne} (or {., nw==ne} at edge)
        f2p d = *(const f2p*)p1;     // {sw, se}
        float r = wa_x * a.x + wa_y * a.y + wb_x * d.x + wb_y * d.y;
        __builtin_nontemporal_store(r, ob);
        p0 += IH * IW;
        p1 += IH * IW;
        ob += BEV_H * BEV_W;
    }
}

extern "C" void kernel_launch(void* const* d_in, const int* in_sizes, int n_in,
                              void* d_out, int out_size, void* d_ws, size_t ws_size,
                              hipStream_t stream) {
    const float* feat    = (const float*)d_in[0];
    const float* rot     = (const float*)d_in[1];
    const float* shift_u = (const float*)d_in[2];
    const float* shift_v = (const float*)d_in[3];
    const float* mpp     = (const float*)d_in[4];
    float* out = (float*)d_out;

    const int total = B_N * BEV_H * BEV_W * GROUPS;  // 2,097,152 threads
    dim3 block(256);
    dim3 grid(total / 256);                          // 8192 blocks
    bev_project_kernel<<<grid, block, 0, stream>>>(feat, rot, shift_u, shift_v, mpp, out);
}